// Round 2
// 754.811 us; speedup vs baseline: 1.9840x; 1.9840x over previous
//
#include <hip/hip_runtime.h>

// Markonv via bf16 split-precision MFMA GEMM.
// out[b,k,p] = sum_{i<16,c1<4,c2<4} x[b,p+i,c1] * x[b,p+i+1,c2] * ker[i,c1,c2,k]
//            = sum_{r<256} q[b, p+i(r), cc(r)] * W[r,k],  q[t,cc]=x[t,c1]*x[t+1,c2]
// Split q and W into bf16 hi+lo; acc += Ah*Bh + Ah*Bl + Al*Bh (fp32 MFMA accum).
// Dropped Al*Bl term is <= 2^-16 relative -> far inside 7.8e-3 tolerance.
//
// x:   [128, 10000, 4] fp32   ker: [16,4,4,128] fp32 -> W[r,k]=ker[r*128+k]
// out: [128, 128, 9984] fp32

#define LL     10000
#define LOUT   9984
#define NK     128
#define NB     128
#define PTILES 156               // tiles of 64 p
#define NTILES (PTILES * NB)     // 19968
#define GRID   2496              // NTILES / 8 -> exactly 8 tiles per block

typedef float f32x4  __attribute__((ext_vector_type(4)));
typedef short short8 __attribute__((ext_vector_type(8)));   // 8 bf16 bit-patterns (4 VGPRs)

static __device__ __forceinline__ unsigned short bf16_trunc(float f) {
    return (unsigned short)(__builtin_bit_cast(unsigned, f) >> 16);
}
static __device__ __forceinline__ float bf16_back(unsigned short h) {
    return __builtin_bit_cast(float, ((unsigned)h) << 16);
}

__global__ __launch_bounds__(256, 2) void markonv_mfma(
    const float* __restrict__ x,
    const float* __restrict__ ker,
    float* __restrict__ out)
{
    __shared__ float wstage[32 * NK];                      // 16 KiB staging for W rows
    __shared__ __align__(16) unsigned short qh_l[79][24];  // q hi, 48B row stride
    __shared__ __align__(16) unsigned short ql_l[79][24];  // q lo

    const int tid  = threadIdx.x;
    const int lane = tid & 63;
    const int wave = tid >> 6;          // 0..3 -> k-slice [wave*32, wave*32+32)
    const int quad = lane >> 4;         // MFMA lane group
    const int col  = lane & 15;

    // ---------------- B fragments: built once per block, live in VGPRs ----------
    // B-frag for (nt, chunk c): lane holds W[r = c*32 + quad*8 + e, k = wave*32+nt*16+col]
    short8 Bh[2][8], Bl[2][8];
    #pragma unroll
    for (int c = 0; c < 8; ++c) {
        __syncthreads();                 // wstage reuse guard
        #pragma unroll
        for (int t = 0; t < 4; ++t)
            ((float4*)wstage)[tid + 256 * t] =
                ((const float4*)(ker + c * 32 * NK))[tid + 256 * t];
        __syncthreads();
        #pragma unroll
        for (int nt = 0; nt < 2; ++nt) {
            #pragma unroll
            for (int e = 0; e < 8; ++e) {
                float w = wstage[(quad * 8 + e) * NK + wave * 32 + nt * 16 + col];
                unsigned short hh = bf16_trunc(w);
                unsigned short hl = bf16_trunc(w - bf16_back(hh));
                Bh[nt][c][e] = (short)hh;
                Bl[nt][c][e] = (short)hl;
            }
        }
    }

    // per-lane A-fragment base byte offset into q arrays:
    // row = (lane&15) + (quad>>1)  [+ mt*16 + 2c at use site], cc-half = quad&1
    const int abase = ((lane & 15) + (quad >> 1)) * 48 + (quad & 1) * 16;
    const char* qh_base = (const char*)qh_l + abase;
    const char* ql_base = (const char*)ql_l + abase;

    for (int tile = blockIdx.x; tile < NTILES; tile += GRID) {
        const int b  = tile & (NB - 1);
        const int p0 = (tile >> 7) * 64;
        const float* xb = x + (size_t)b * (LL * 4);

        __syncthreads();                 // q arrays: previous readers done
        if (tid < 79) {                  // rows t = p0 .. p0+78  (t+1 <= 9999)
            const float4 xa = *(const float4*)(xb + (size_t)(p0 + tid) * 4);
            const float4 xn = *(const float4*)(xb + (size_t)(p0 + tid + 1) * 4);
            const float a4[4] = {xa.x, xa.y, xa.z, xa.w};
            const float n4[4] = {xn.x, xn.y, xn.z, xn.w};
            #pragma unroll
            for (int c1 = 0; c1 < 4; ++c1) {
                #pragma unroll
                for (int c2 = 0; c2 < 4; ++c2) {
                    float q = a4[c1] * n4[c2];
                    unsigned short hh = bf16_trunc(q);
                    unsigned short hl = bf16_trunc(q - bf16_back(hh));
                    qh_l[tid][c1 * 4 + c2] = hh;
                    ql_l[tid][c1 * 4 + c2] = hl;
                }
            }
        }
        __syncthreads();

        f32x4 acc[4][2];
        #pragma unroll
        for (int mt = 0; mt < 4; ++mt)
            #pragma unroll
            for (int nt = 0; nt < 2; ++nt)
                acc[mt][nt] = (f32x4){0.f, 0.f, 0.f, 0.f};

        // K-loop: 8 chunks of 32 (2 kernel taps each)
        #pragma unroll
        for (int c = 0; c < 8; ++c) {
            short8 Ah[4], Al[4];
            #pragma unroll
            for (int mt = 0; mt < 4; ++mt) {
                const int off = mt * 768 + c * 96;   // (mt*16 + 2c) rows * 48B
                Ah[mt] = *(const short8*)(qh_base + off);
                Al[mt] = *(const short8*)(ql_base + off);
            }
            #pragma unroll
            for (int mt = 0; mt < 4; ++mt) {
                #pragma unroll
                for (int nt = 0; nt < 2; ++nt) {
                    acc[mt][nt] = __builtin_amdgcn_mfma_f32_16x16x32_bf16(
                        Ah[mt], Bh[nt][c], acc[mt][nt], 0, 0, 0);
                    acc[mt][nt] = __builtin_amdgcn_mfma_f32_16x16x32_bf16(
                        Ah[mt], Bl[nt][c], acc[mt][nt], 0, 0, 0);
                    acc[mt][nt] = __builtin_amdgcn_mfma_f32_16x16x32_bf16(
                        Al[mt], Bh[nt][c], acc[mt][nt], 0, 0, 0);
                }
            }
        }

        // C/D layout (m89-verified): col = lane&15 (-> k), row = quad*4 + reg (-> p)
        #pragma unroll
        for (int mt = 0; mt < 4; ++mt) {
            #pragma unroll
            for (int nt = 0; nt < 2; ++nt) {
                const int k = wave * 32 + nt * 16 + col;
                const int p = p0 + mt * 16 + quad * 4;
                *(f32x4*)(out + ((size_t)b * NK + k) * LOUT + p) = acc[mt][nt];
            }
        }
    }
}

extern "C" void kernel_launch(void* const* d_in, const int* in_sizes, int n_in,
                              void* d_out, int out_size, void* d_ws, size_t ws_size,
                              hipStream_t stream)
{
    const float* x   = (const float*)d_in[0];
    const float* ker = (const float*)d_in[1];
    float* out       = (float*)d_out;

    markonv_mfma<<<dim3(GRID), dim3(256), 0, stream>>>(x, ker, out);
}